// Round 9
// baseline (137.150 us; speedup 1.0000x reference)
//
#include <hip/hip_runtime.h>

#define HID 20

typedef _Float16 half8  __attribute__((ext_vector_type(8)));
typedef _Float16 half2t __attribute__((ext_vector_type(2)));
typedef float    f32x16 __attribute__((ext_vector_type(16)));

union H8 { half8 v8; half2t d[4]; };   // build fp16 fragment dword-by-dword

// tanh via exp2 + rcp: tanh(v) = 1 - 2/(exp2(v*2*log2e)+1). Saturates at +-inf.
static __device__ __forceinline__ float tanh_fast(float v) {
    const float e = __builtin_amdgcn_exp2f(v * 2.8853900817779268f);
    const float r = __builtin_amdgcn_rcpf(e + 1.0f);
    return fmaf(-2.0f, r, 1.0f);
}

// v_cvt_pkrtz_f16_f32: pack two f32 into one dword of two fp16 (RTZ).
static __device__ __forceinline__ half2t pk(float a, float b) {
    auto r = __builtin_amdgcn_cvt_pkrtz(a, b);
    half2t out;
    __builtin_memcpy(&out, &r, sizeof(out));
    return out;
}

// v_permlane32_swap_b32: new_x[l>=32] = old_y[l-32]; new_y[l<32] = old_x[l+32].
static __device__ __forceinline__ void swap_halves(float& x, float& y) {
    asm("v_permlane32_swap_b32 %0, %1" : "+v"(x), "+v"(y));
}

// sum with lane^32 partner on every lane: permlane-based, no LDS wait.
static __device__ __forceinline__ float xor32_sum(float u) {
    float t = u;
    swap_halves(u, t);     // u[l] = old_u[l&31]; t[l] = old_u[32|(l&31)]
    return u + t;
}

// 64-lane shuffle reduce -> cross-wave LDS -> one f64 atomic per block.
__device__ __forceinline__ void block_reduce_atomic(float local, double* dst) {
    #pragma unroll
    for (int off = 32; off > 0; off >>= 1) local += __shfl_down(local, off);
    __shared__ float parts[4];
    __syncthreads();
    const int lane = threadIdx.x & 63, wid = threadIdx.x >> 6;
    if (lane == 0) parts[wid] = local;
    __syncthreads();
    if (threadIdx.x == 0)
        atomicAdd(dst, (double)(parts[0] + parts[1] + parts[2] + parts[3]));
}

// ---------------------------------------------------------------------------
// Fused kernel (round-5 proven config: grid 2560, bounds(256,3), oversubscribed
// grid-stride for self-balancing). Blocks [0,CBLK): collocation (4 dual
// channels); [CBLK,CBLK+DBLK): initial+boundary (value only).
// Swapped MFMA orientation: D = Wt * Ht, point = column = lane&31 for B and D.
//   A (Wt): M-row = lane&31 (out neuron), k = 16c + 8h + e (in neuron);
//           k==20 carries the bias; rows/cols >= 20 are zero.
//   D:      col = lane&31 (point), row = (r&3) + 8(r>>2) + 4h.
// Rows >= 20 of D are exactly 0 => epilogue only r<12; pack c=1 needs no swap.
// Last finishing block computes the final loss (folded k_fin).
// ---------------------------------------------------------------------------
__global__ __launch_bounds__(256, 3) void k_fused(
    const float* __restrict__ t_c, const float* __restrict__ x_c,
    const float* __restrict__ t_i, const float* __restrict__ x_i, const float* __restrict__ u_i,
    const float* __restrict__ t_b, const float* __restrict__ x_b, const float* __restrict__ u_b,
    const float* __restrict__ W1, const float* __restrict__ b1,
    const float* __restrict__ W2, const float* __restrict__ b2,
    const float* __restrict__ W3, const float* __restrict__ b3,
    const float* __restrict__ W4, const float* __restrict__ b4,
    double* __restrict__ sums, unsigned* __restrict__ done_cnt,
    float* __restrict__ out,
    int N, int NI, int NB, int CBLK, int DBLK, float nu)
{
    __shared__ float4 sL[32];          // {W1_t, W1_x, b1, 0} per layer-1 slot
    const int tid = threadIdx.x;
    if (tid < 32) {
        const bool r = tid < HID;
        sL[tid] = make_float4(r ? W1[tid] : 0.f, r ? W1[HID + tid] : 0.f,
                              r ? b1[tid] : 0.f, 0.f);
    }
    __syncthreads();

    const int lane = tid & 63;
    const int h    = lane >> 5;
    const int colp = lane & 31;

    // A fragments for W2,W3 (+bias row k=20); W4 in D layout (live rows only)
    half8 A2[2], A3[2];
    #pragma unroll
    for (int c = 0; c < 2; ++c) {
        #pragma unroll
        for (int e = 0; e < 8; ++e) {
            const int i = 16 * c + 8 * h + e;
            float v2 = 0.f, v3 = 0.f;
            if (colp < HID) {
                if (i < HID)       { v2 = W2[i * HID + colp]; v3 = W3[i * HID + colp]; }
                else if (i == HID) { v2 = b2[colp];           v3 = b3[colp]; }
            }
            A2[c][e] = (_Float16)v2;
            A3[c][e] = (_Float16)v3;
        }
    }
    float w4v[12];
    #pragma unroll
    for (int r = 0; r < 12; ++r) {
        const int row = (r & 3) + 8 * (r >> 2) + 4 * h;
        w4v[r] = (row < HID) ? W4[row] : 0.0f;
    }
    const float b4v = b4[0];
    const half2t Z2   = {(_Float16)0.0f, (_Float16)0.0f};
    const half2t ONE0 = {(_Float16)1.0f, (_Float16)0.0f};
    // persistent zero accumulator: C operand of each channel's first MFMA chunk
    f32x16 FZ;
    #pragma unroll
    for (int r = 0; r < 16; ++r) FZ[r] = 0.0f;

    if ((int)blockIdx.x < CBLK) {
        // ================= collocation: 4 dual channels =================
        const int wave  = (int)blockIdx.x * 4 + (tid >> 6);
        const int nwave = CBLK * 4;
        const int ntile = (N + 31) >> 5;

        float local = 0.0f;
        int  tile  = wave;
        bool valid = false;
        float tv = 0.f, xv = 0.f;
        if (tile < ntile) {
            const int idx = (tile << 5) + colp;
            valid = idx < N;
            const int ia = valid ? idx : 0;
            tv = t_c[ia]; xv = x_c[ia];
        }
        while (tile < ntile) {
            // ---- prefetch next tile's inputs (issue before the body) ----
            const int nxt = tile + nwave;
            float ntv = 0.f, nxv = 0.f;
            bool nvalid = false;
            if (nxt < ntile) {
                const int nidx = (nxt << 5) + colp;
                nvalid = nidx < N;
                const int nia = nvalid ? nidx : 0;
                ntv = t_c[nia]; nxv = x_c[nia];
            }

            // layer-1 slot: p = t*w.x + x*w.y + w.z ; duals from (w.x, w.y)
            auto l1 = [&](int e, int c, float& vv, float& va, float& vc, float& ve) {
                const int n = 16 * c + 8 * h + e;
                const float4 w = sL[n];
                const float p  = fmaf(tv, w.x, fmaf(xv, w.y, w.z));
                const float th = tanh_fast(p);
                const float s  = fmaf(-th, th, 1.0f);
                const float q  = s * w.y;
                vv = th; va = s * w.x; vc = q; ve = -((th + th) * q) * w.y;
            };

            H8 Bv[2], Ba[2], Bc[2], Be[2];
            #pragma unroll
            for (int d2 = 0; d2 < 4; ++d2) {       // c=0, slot pairs
                float v0,a0,c0,e0, v1,a1,c1,e1;
                l1(2*d2,     0, v0,a0,c0,e0);
                l1(2*d2 + 1, 0, v1,a1,c1,e1);
                Bv[0].d[d2] = pk(v0,v1); Ba[0].d[d2] = pk(a0,a1);
                Bc[0].d[d2] = pk(c0,c1); Be[0].d[d2] = pk(e0,e1);
            }
            #pragma unroll
            for (int d2 = 0; d2 < 2; ++d2) {       // c=1, slots 16..19
                float v0,a0,c0,e0, v1,a1,c1,e1;
                l1(2*d2,     1, v0,a0,c0,e0);
                l1(2*d2 + 1, 1, v1,a1,c1,e1);
                Bv[1].d[d2] = pk(v0,v1); Ba[1].d[d2] = pk(a0,a1);
                Bc[1].d[d2] = pk(c0,c1); Be[1].d[d2] = pk(e0,e1);
            }
            Bv[1].d[2] = ONE0; Ba[1].d[2] = Z2; Bc[1].d[2] = Z2; Be[1].d[2] = Z2; // bias k=20
            Bv[1].d[3] = Z2;   Ba[1].d[3] = Z2; Bc[1].d[3] = Z2; Be[1].d[3] = Z2;

            // ---- layer 2: first chunk takes FZ as C (no per-tile zeroing) ----
            f32x16 Dv, Da, Dc, De;
            Dv = __builtin_amdgcn_mfma_f32_32x32x16_f16(A2[0], Bv[0].v8, FZ, 0,0,0);
            Da = __builtin_amdgcn_mfma_f32_32x32x16_f16(A2[0], Ba[0].v8, FZ, 0,0,0);
            Dc = __builtin_amdgcn_mfma_f32_32x32x16_f16(A2[0], Bc[0].v8, FZ, 0,0,0);
            De = __builtin_amdgcn_mfma_f32_32x32x16_f16(A2[0], Be[0].v8, FZ, 0,0,0);
            Dv = __builtin_amdgcn_mfma_f32_32x32x16_f16(A2[1], Bv[1].v8, Dv, 0,0,0);
            Da = __builtin_amdgcn_mfma_f32_32x32x16_f16(A2[1], Ba[1].v8, Da, 0,0,0);
            Dc = __builtin_amdgcn_mfma_f32_32x32x16_f16(A2[1], Bc[1].v8, Dc, 0,0,0);
            De = __builtin_amdgcn_mfma_f32_32x32x16_f16(A2[1], Be[1].v8, De, 0,0,0);

            #pragma unroll
            for (int r = 0; r < 12; ++r) {          // rows >=24 are dead
                const float zv = Dv[r], za = Da[r], zc = Dc[r], ze = De[r];
                const float th = tanh_fast(zv);
                const float s  = fmaf(-th, th, 1.0f);
                const float q  = s * zc;
                Dv[r] = th; Da[r] = s * za; Dc[r] = q;
                De[r] = fmaf(s, ze, -((th + th) * q) * zc);
            }
            // pack D -> B: c=0 via swaps; c=1 straight (h=1 side is natural 0)
            #pragma unroll
            for (int d2 = 0; d2 < 2; ++d2) {
                float x0,y0,x1,y1;
                x0=Dv[2*d2]; y0=Dv[4+2*d2]; swap_halves(x0,y0);
                x1=Dv[2*d2+1]; y1=Dv[5+2*d2]; swap_halves(x1,y1);
                Bv[0].d[d2] = pk(x0,x1); Bv[0].d[2+d2] = pk(y0,y1);
                x0=Da[2*d2]; y0=Da[4+2*d2]; swap_halves(x0,y0);
                x1=Da[2*d2+1]; y1=Da[5+2*d2]; swap_halves(x1,y1);
                Ba[0].d[d2] = pk(x0,x1); Ba[0].d[2+d2] = pk(y0,y1);
                x0=Dc[2*d2]; y0=Dc[4+2*d2]; swap_halves(x0,y0);
                x1=Dc[2*d2+1]; y1=Dc[5+2*d2]; swap_halves(x1,y1);
                Bc[0].d[d2] = pk(x0,x1); Bc[0].d[2+d2] = pk(y0,y1);
                x0=De[2*d2]; y0=De[4+2*d2]; swap_halves(x0,y0);
                x1=De[2*d2+1]; y1=De[5+2*d2]; swap_halves(x1,y1);
                Be[0].d[d2] = pk(x0,x1); Be[0].d[2+d2] = pk(y0,y1);
            }
            Bv[1].d[0] = pk(Dv[8],Dv[9]); Bv[1].d[1] = pk(Dv[10],Dv[11]);
            Ba[1].d[0] = pk(Da[8],Da[9]); Ba[1].d[1] = pk(Da[10],Da[11]);
            Bc[1].d[0] = pk(Dc[8],Dc[9]); Bc[1].d[1] = pk(Dc[10],Dc[11]);
            Be[1].d[0] = pk(De[8],De[9]); Be[1].d[1] = pk(De[10],De[11]);
            Bv[1].d[2] = ONE0; Ba[1].d[2] = Z2; Bc[1].d[2] = Z2; Be[1].d[2] = Z2;
            Bv[1].d[3] = Z2;   Ba[1].d[3] = Z2; Bc[1].d[3] = Z2; Be[1].d[3] = Z2;

            // ---- layer 3 ----
            Dv = __builtin_amdgcn_mfma_f32_32x32x16_f16(A3[0], Bv[0].v8, FZ, 0,0,0);
            Da = __builtin_amdgcn_mfma_f32_32x32x16_f16(A3[0], Ba[0].v8, FZ, 0,0,0);
            Dc = __builtin_amdgcn_mfma_f32_32x32x16_f16(A3[0], Bc[0].v8, FZ, 0,0,0);
            De = __builtin_amdgcn_mfma_f32_32x32x16_f16(A3[0], Be[0].v8, FZ, 0,0,0);
            Dv = __builtin_amdgcn_mfma_f32_32x32x16_f16(A3[1], Bv[1].v8, Dv, 0,0,0);
            Da = __builtin_amdgcn_mfma_f32_32x32x16_f16(A3[1], Ba[1].v8, Da, 0,0,0);
            Dc = __builtin_amdgcn_mfma_f32_32x32x16_f16(A3[1], Bc[1].v8, Dc, 0,0,0);
            De = __builtin_amdgcn_mfma_f32_32x32x16_f16(A3[1], Be[1].v8, De, 0,0,0);

            #pragma unroll
            for (int r = 0; r < 12; ++r) {
                const float zv = Dv[r], za = Da[r], zc = Dc[r], ze = De[r];
                const float th = tanh_fast(zv);
                const float s  = fmaf(-th, th, 1.0f);
                const float q  = s * zc;
                Dv[r] = th; Da[r] = s * za; Dc[r] = q;
                De[r] = fmaf(s, ze, -((th + th) * q) * zc);
            }

            float u = 0.f, ut = 0.f, ux = 0.f, uxx = 0.f;
            #pragma unroll
            for (int r = 0; r < 12; ++r) {
                u   = fmaf(w4v[r], Dv[r], u);
                ut  = fmaf(w4v[r], Da[r], ut);
                ux  = fmaf(w4v[r], Dc[r], ux);
                uxx = fmaf(w4v[r], De[r], uxx);
            }
            u   = xor32_sum(u) + b4v;
            ut  = xor32_sum(ut);
            ux  = xor32_sum(ux);
            uxx = xor32_sum(uxx);

            float f = fmaf(u, ux, ut);
            f = fmaf(-nu, uxx, f);
            if (h == 0 && valid) local += f * f;

            tv = ntv; xv = nxv; valid = nvalid; tile = nxt;
        }
        block_reduce_atomic(local, sums + 0);
    } else {
        // ============== initial + boundary: value channel only ==============
        const int dwave = ((int)blockIdx.x - CBLK) * 4 + (tid >> 6);
        const int dnw   = DBLK * 4;
        const int nti   = (NI + 31) >> 5;
        const int ntb   = (NB + 31) >> 5;

        float li = 0.0f, lbd = 0.0f;
        for (int t2 = dwave; t2 < nti + ntb; t2 += dnw) {
            const bool isB = t2 >= nti;               // wave-uniform
            const float* tp = isB ? t_b : t_i;
            const float* xp = isB ? x_b : x_i;
            const float* up = isB ? u_b : u_i;
            const int    n_ = isB ? NB  : NI;
            const int  idx  = (((isB ? t2 - nti : t2) << 5)) + colp;
            const bool valid = idx < n_;
            const int  ia    = valid ? idx : 0;
            const float tv = tp[ia], xv = xp[ia], uT = up[ia];

            auto l1v = [&](int e, int c) -> float {
                const int n = 16 * c + 8 * h + e;
                const float4 w = sL[n];
                return tanh_fast(fmaf(tv, w.x, fmaf(xv, w.y, w.z)));
            };

            H8 Bv[2];
            #pragma unroll
            for (int d2 = 0; d2 < 4; ++d2)
                Bv[0].d[d2] = pk(l1v(2*d2, 0), l1v(2*d2+1, 0));
            #pragma unroll
            for (int d2 = 0; d2 < 2; ++d2)
                Bv[1].d[d2] = pk(l1v(2*d2, 1), l1v(2*d2+1, 1));
            Bv[1].d[2] = ONE0; Bv[1].d[3] = Z2;

            f32x16 Dv;
            Dv = __builtin_amdgcn_mfma_f32_32x32x16_f16(A2[0], Bv[0].v8, FZ, 0,0,0);
            Dv = __builtin_amdgcn_mfma_f32_32x32x16_f16(A2[1], Bv[1].v8, Dv, 0,0,0);
            #pragma unroll
            for (int r = 0; r < 12; ++r) Dv[r] = tanh_fast(Dv[r]);

            #pragma unroll
            for (int d2 = 0; d2 < 2; ++d2) {
                float x0,y0,x1,y1;
                x0=Dv[2*d2]; y0=Dv[4+2*d2]; swap_halves(x0,y0);
                x1=Dv[2*d2+1]; y1=Dv[5+2*d2]; swap_halves(x1,y1);
                Bv[0].d[d2] = pk(x0,x1); Bv[0].d[2+d2] = pk(y0,y1);
            }
            Bv[1].d[0] = pk(Dv[8],Dv[9]); Bv[1].d[1] = pk(Dv[10],Dv[11]);
            Bv[1].d[2] = ONE0; Bv[1].d[3] = Z2;

            Dv = __builtin_amdgcn_mfma_f32_32x32x16_f16(A3[0], Bv[0].v8, FZ, 0,0,0);
            Dv = __builtin_amdgcn_mfma_f32_32x32x16_f16(A3[1], Bv[1].v8, Dv, 0,0,0);
            #pragma unroll
            for (int r = 0; r < 12; ++r) Dv[r] = tanh_fast(Dv[r]);

            float u = 0.f;
            #pragma unroll
            for (int r = 0; r < 12; ++r) u = fmaf(w4v[r], Dv[r], u);
            u = xor32_sum(u) + b4v;
            const float dd = u - uT;
            if (h == 0 && valid) { if (isB) lbd += dd * dd; else li += dd * dd; }
        }
        block_reduce_atomic(li,  sums + 1);
        block_reduce_atomic(lbd, sums + 2);
    }

    // ---- folded finalize: last block to finish computes the loss ----
    if (threadIdx.x == 0) {
        __threadfence();                                  // sums visible first
        const unsigned old = atomicAdd(done_cnt, 1u);
        if (old == (unsigned)(CBLK + DBLK - 1)) {
            const double s0 = atomicAdd(&sums[0], 0.0);   // device-scope reads
            const double s1 = atomicAdd(&sums[1], 0.0);
            const double s2 = atomicAdd(&sums[2], 0.0);
            out[0] = (float)(s0 / (double)N + s1 / (double)NI + s2 / (double)NB);
        }
    }
}

__global__ void k_zero(double* sums) {
    if (threadIdx.x < 3) sums[threadIdx.x] = 0.0;
    if (threadIdx.x == 3) *((unsigned*)(sums + 3)) = 0u;
}

extern "C" void kernel_launch(void* const* d_in, const int* in_sizes, int n_in,
                              void* d_out, int out_size, void* d_ws, size_t ws_size,
                              hipStream_t stream) {
    const float* t_c = (const float*)d_in[0];
    const float* x_c = (const float*)d_in[1];
    const float* t_i = (const float*)d_in[2];
    const float* x_i = (const float*)d_in[3];
    const float* u_i = (const float*)d_in[4];
    const float* t_b = (const float*)d_in[5];
    const float* x_b = (const float*)d_in[6];
    const float* u_b = (const float*)d_in[7];
    const float* W1  = (const float*)d_in[8];
    const float* b1  = (const float*)d_in[9];
    const float* W2  = (const float*)d_in[10];
    const float* b2  = (const float*)d_in[11];
    const float* W3  = (const float*)d_in[12];
    const float* b3  = (const float*)d_in[13];
    const float* W4  = (const float*)d_in[14];
    const float* b4  = (const float*)d_in[15];

    const int N  = in_sizes[0];
    const int NI = in_sizes[2];
    const int NB = in_sizes[5];
    const float nu = 0.0031830988618379067f;  // 0.01/pi

    // Oversubscribed grid (proven 103us config): 2560 blocks over ~768
    // resident slots self-balances coll vs data cost mismatch.
    const int CBLK = 2048;
    const int DBLK = 512;

    double*   sums = (double*)d_ws;
    unsigned* cnt  = (unsigned*)(sums + 3);

    k_zero<<<1, 64, 0, stream>>>(sums);
    k_fused<<<CBLK + DBLK, 256, 0, stream>>>(t_c, x_c, t_i, x_i, u_i, t_b, x_b, u_b,
                                             W1, b1, W2, b2, W3, b3, W4, b4,
                                             sums, cnt, (float*)d_out,
                                             N, NI, NB, CBLK, DBLK, nu);
}

// Round 10
// 105.633 us; speedup vs baseline: 1.2984x; 1.2984x over previous
//
#include <hip/hip_runtime.h>

#define HID 20

typedef _Float16 half8  __attribute__((ext_vector_type(8)));
typedef _Float16 half2t __attribute__((ext_vector_type(2)));
typedef float    f32x16 __attribute__((ext_vector_type(16)));

union H8 { half8 v8; half2t d[4]; };   // build fp16 fragment dword-by-dword

// tanh via exp2 + rcp: tanh(v) = 1 - 2/(exp2(v*2*log2e)+1). Saturates at +-inf.
static __device__ __forceinline__ float tanh_fast(float v) {
    const float e = __builtin_amdgcn_exp2f(v * 2.8853900817779268f);
    const float r = __builtin_amdgcn_rcpf(e + 1.0f);
    return fmaf(-2.0f, r, 1.0f);
}

// v_cvt_pkrtz_f16_f32: pack two f32 into one dword of two fp16 (RTZ).
static __device__ __forceinline__ half2t pk(float a, float b) {
    auto r = __builtin_amdgcn_cvt_pkrtz(a, b);
    half2t out;
    __builtin_memcpy(&out, &r, sizeof(out));
    return out;
}

// v_permlane32_swap_b32: new_x[l>=32] = old_y[l-32]; new_y[l<32] = old_x[l+32].
static __device__ __forceinline__ void swap_halves(float& x, float& y) {
    asm("v_permlane32_swap_b32 %0, %1" : "+v"(x), "+v"(y));
}

// sum with lane^32 partner on every lane: permlane-based, no LDS wait.
static __device__ __forceinline__ float xor32_sum(float u) {
    float t = u;
    swap_halves(u, t);
    return u + t;
}

// 64-lane shuffle reduce -> cross-wave LDS -> one f64 atomic per block.
__device__ __forceinline__ void block_reduce_atomic(float local, double* dst) {
    #pragma unroll
    for (int off = 32; off > 0; off >>= 1) local += __shfl_down(local, off);
    __shared__ float parts[4];
    __syncthreads();
    const int lane = threadIdx.x & 63, wid = threadIdx.x >> 6;
    if (lane == 0) parts[wid] = local;
    __syncthreads();
    if (threadIdx.x == 0)
        atomicAdd(dst, (double)(parts[0] + parts[1] + parts[2] + parts[3]));
}

// ---------------------------------------------------------------------------
// Fused kernel, UNIFIED work queue: every wave grid-strides over the combined
// tile space [0, ntc+nti+ntb) and branches per tile (wave-uniform) on class.
// This self-balances coll vs data cost AND removes the dispatch tail
// (768 blocks = 3/CU exactly; each wave gets the same ~20 coll + 4 data mix).
// Swapped MFMA orientation: D = Wt * Ht, point = column = lane&31 for B and D.
//   A (Wt): M-row = lane&31 (out neuron), k = 16c + 8h + e (in neuron);
//           k==20 carries the bias; rows/cols >= 20 are zero.
//   D:      col = lane&31 (point), row = (r&3) + 8(r>>2) + 4h.
// Rows >= 20 of D are exactly 0 => epilogue only r<12; pack c=1 needs no swap.
// __launch_bounds__(256,3): ~70 arch + 64 acc regs, 3 waves/SIMD, no spill.
// (256,4) forces arch<=64 -> 22 MB scratch spill (measured round 7).
// Folded finalize also triggers spill (measured round 9) -> separate k_fin.
// ---------------------------------------------------------------------------
__global__ __launch_bounds__(256, 3) void k_fused(
    const float* __restrict__ t_c, const float* __restrict__ x_c,
    const float* __restrict__ t_i, const float* __restrict__ x_i, const float* __restrict__ u_i,
    const float* __restrict__ t_b, const float* __restrict__ x_b, const float* __restrict__ u_b,
    const float* __restrict__ W1, const float* __restrict__ b1,
    const float* __restrict__ W2, const float* __restrict__ b2,
    const float* __restrict__ W3, const float* __restrict__ b3,
    const float* __restrict__ W4, const float* __restrict__ b4,
    double* __restrict__ sums,
    int N, int NI, int NB, float nu)
{
    __shared__ float4 sL[32];          // {W1_t, W1_x, b1, 0} per layer-1 slot
    const int tid = threadIdx.x;
    if (tid < 32) {
        const bool r = tid < HID;
        sL[tid] = make_float4(r ? W1[tid] : 0.f, r ? W1[HID + tid] : 0.f,
                              r ? b1[tid] : 0.f, 0.f);
    }
    __syncthreads();

    const int lane = tid & 63;
    const int h    = lane >> 5;
    const int colp = lane & 31;

    // A fragments for W2,W3 (+bias row k=20); W4 in D layout (live rows only)
    half8 A2[2], A3[2];
    #pragma unroll
    for (int c = 0; c < 2; ++c) {
        #pragma unroll
        for (int e = 0; e < 8; ++e) {
            const int i = 16 * c + 8 * h + e;
            float v2 = 0.f, v3 = 0.f;
            if (colp < HID) {
                if (i < HID)       { v2 = W2[i * HID + colp]; v3 = W3[i * HID + colp]; }
                else if (i == HID) { v2 = b2[colp];           v3 = b3[colp]; }
            }
            A2[c][e] = (_Float16)v2;
            A3[c][e] = (_Float16)v3;
        }
    }
    float w4v[12];
    #pragma unroll
    for (int r = 0; r < 12; ++r) {
        const int row = (r & 3) + 8 * (r >> 2) + 4 * h;
        w4v[r] = (row < HID) ? W4[row] : 0.0f;
    }
    const float b4v = b4[0];
    const half2t Z2   = {(_Float16)0.0f, (_Float16)0.0f};
    const half2t ONE0 = {(_Float16)1.0f, (_Float16)0.0f};
    // persistent zero accumulator: C operand of each channel's first MFMA chunk
    f32x16 FZ;
    #pragma unroll
    for (int r = 0; r < 16; ++r) FZ[r] = 0.0f;

    const int ntc  = (N  + 31) >> 5;
    const int nti  = (NI + 31) >> 5;
    const int ntb  = (NB + 31) >> 5;
    const int ntot = ntc + nti + ntb;
    const int gw   = (int)blockIdx.x * 4 + (tid >> 6);
    const int nw   = (int)gridDim.x * 4;

    // fetch inputs for unified tile index t2 (class-aware); wave-uniform t2.
    auto fetch = [&](int t2, float& ftv, float& fxv, float& fuT, bool& fvalid) {
        if (t2 < ntc) {
            const int idx = (t2 << 5) + colp;
            fvalid = idx < N;
            const int ia = fvalid ? idx : 0;
            ftv = t_c[ia]; fxv = x_c[ia]; fuT = 0.f;
        } else {
            const bool isB = t2 >= ntc + nti;
            const float* tp = isB ? t_b : t_i;
            const float* xp = isB ? x_b : x_i;
            const float* up = isB ? u_b : u_i;
            const int    n_ = isB ? NB  : NI;
            const int  base = t2 - ntc - (isB ? nti : 0);
            const int  idx  = (base << 5) + colp;
            fvalid = idx < n_;
            const int ia = fvalid ? idx : 0;
            ftv = tp[ia]; fxv = xp[ia]; fuT = up[ia];
        }
    };

    float lc = 0.f, li = 0.f, lb = 0.f;

    int  t = gw;
    float tv = 0.f, xv = 0.f, uT = 0.f;
    bool valid = false;
    if (t < ntot) fetch(t, tv, xv, uT, valid);

    while (t < ntot) {
        // ---- software prefetch of next tile's inputs (cross-class aware) ----
        const int nxt = t + nw;
        float ntv = 0.f, nxv = 0.f, nuT = 0.f;
        bool nvalid = false;
        if (nxt < ntot) fetch(nxt, ntv, nxv, nuT, nvalid);

        if (t < ntc) {
            // ================= collocation: 4 dual channels =================
            auto l1 = [&](int e, int c, float& vv, float& va, float& vc, float& ve) {
                const int n = 16 * c + 8 * h + e;
                const float4 w = sL[n];
                const float p  = fmaf(tv, w.x, fmaf(xv, w.y, w.z));
                const float th = tanh_fast(p);
                const float s  = fmaf(-th, th, 1.0f);
                const float q  = s * w.y;
                vv = th; va = s * w.x; vc = q; ve = -((th + th) * q) * w.y;
            };

            H8 Bv[2], Ba[2], Bc[2], Be[2];
            #pragma unroll
            for (int d2 = 0; d2 < 4; ++d2) {       // c=0, slot pairs
                float v0,a0,c0,e0, v1,a1,c1,e1;
                l1(2*d2,     0, v0,a0,c0,e0);
                l1(2*d2 + 1, 0, v1,a1,c1,e1);
                Bv[0].d[d2] = pk(v0,v1); Ba[0].d[d2] = pk(a0,a1);
                Bc[0].d[d2] = pk(c0,c1); Be[0].d[d2] = pk(e0,e1);
            }
            #pragma unroll
            for (int d2 = 0; d2 < 2; ++d2) {       // c=1, slots 16..19
                float v0,a0,c0,e0, v1,a1,c1,e1;
                l1(2*d2,     1, v0,a0,c0,e0);
                l1(2*d2 + 1, 1, v1,a1,c1,e1);
                Bv[1].d[d2] = pk(v0,v1); Ba[1].d[d2] = pk(a0,a1);
                Bc[1].d[d2] = pk(c0,c1); Be[1].d[d2] = pk(e0,e1);
            }
            Bv[1].d[2] = ONE0; Ba[1].d[2] = Z2; Bc[1].d[2] = Z2; Be[1].d[2] = Z2;
            Bv[1].d[3] = Z2;   Ba[1].d[3] = Z2; Bc[1].d[3] = Z2; Be[1].d[3] = Z2;

            // ---- layer 2: first chunk takes FZ as C (no per-tile zeroing) ----
            f32x16 Dv, Da, Dc, De;
            Dv = __builtin_amdgcn_mfma_f32_32x32x16_f16(A2[0], Bv[0].v8, FZ, 0,0,0);
            Da = __builtin_amdgcn_mfma_f32_32x32x16_f16(A2[0], Ba[0].v8, FZ, 0,0,0);
            Dc = __builtin_amdgcn_mfma_f32_32x32x16_f16(A2[0], Bc[0].v8, FZ, 0,0,0);
            De = __builtin_amdgcn_mfma_f32_32x32x16_f16(A2[0], Be[0].v8, FZ, 0,0,0);
            Dv = __builtin_amdgcn_mfma_f32_32x32x16_f16(A2[1], Bv[1].v8, Dv, 0,0,0);
            Da = __builtin_amdgcn_mfma_f32_32x32x16_f16(A2[1], Ba[1].v8, Da, 0,0,0);
            Dc = __builtin_amdgcn_mfma_f32_32x32x16_f16(A2[1], Bc[1].v8, Dc, 0,0,0);
            De = __builtin_amdgcn_mfma_f32_32x32x16_f16(A2[1], Be[1].v8, De, 0,0,0);

            #pragma unroll
            for (int r = 0; r < 12; ++r) {          // rows >=24 are dead
                const float zv = Dv[r], za = Da[r], zc = Dc[r], ze = De[r];
                const float th = tanh_fast(zv);
                const float s  = fmaf(-th, th, 1.0f);
                const float q  = s * zc;
                Dv[r] = th; Da[r] = s * za; Dc[r] = q;
                De[r] = fmaf(s, ze, -((th + th) * q) * zc);
            }
            // pack D -> B: c=0 via swaps; c=1 straight (h=1 side is natural 0)
            #pragma unroll
            for (int d2 = 0; d2 < 2; ++d2) {
                float x0,y0,x1,y1;
                x0=Dv[2*d2]; y0=Dv[4+2*d2]; swap_halves(x0,y0);
                x1=Dv[2*d2+1]; y1=Dv[5+2*d2]; swap_halves(x1,y1);
                Bv[0].d[d2] = pk(x0,x1); Bv[0].d[2+d2] = pk(y0,y1);
                x0=Da[2*d2]; y0=Da[4+2*d2]; swap_halves(x0,y0);
                x1=Da[2*d2+1]; y1=Da[5+2*d2]; swap_halves(x1,y1);
                Ba[0].d[d2] = pk(x0,x1); Ba[0].d[2+d2] = pk(y0,y1);
                x0=Dc[2*d2]; y0=Dc[4+2*d2]; swap_halves(x0,y0);
                x1=Dc[2*d2+1]; y1=Dc[5+2*d2]; swap_halves(x1,y1);
                Bc[0].d[d2] = pk(x0,x1); Bc[0].d[2+d2] = pk(y0,y1);
                x0=De[2*d2]; y0=De[4+2*d2]; swap_halves(x0,y0);
                x1=De[2*d2+1]; y1=De[5+2*d2]; swap_halves(x1,y1);
                Be[0].d[d2] = pk(x0,x1); Be[0].d[2+d2] = pk(y0,y1);
            }
            Bv[1].d[0] = pk(Dv[8],Dv[9]); Bv[1].d[1] = pk(Dv[10],Dv[11]);
            Ba[1].d[0] = pk(Da[8],Da[9]); Ba[1].d[1] = pk(Da[10],Da[11]);
            Bc[1].d[0] = pk(Dc[8],Dc[9]); Bc[1].d[1] = pk(Dc[10],Dc[11]);
            Be[1].d[0] = pk(De[8],De[9]); Be[1].d[1] = pk(De[10],De[11]);
            Bv[1].d[2] = ONE0; Ba[1].d[2] = Z2; Bc[1].d[2] = Z2; Be[1].d[2] = Z2;
            Bv[1].d[3] = Z2;   Ba[1].d[3] = Z2; Bc[1].d[3] = Z2; Be[1].d[3] = Z2;

            // ---- layer 3 ----
            Dv = __builtin_amdgcn_mfma_f32_32x32x16_f16(A3[0], Bv[0].v8, FZ, 0,0,0);
            Da = __builtin_amdgcn_mfma_f32_32x32x16_f16(A3[0], Ba[0].v8, FZ, 0,0,0);
            Dc = __builtin_amdgcn_mfma_f32_32x32x16_f16(A3[0], Bc[0].v8, FZ, 0,0,0);
            De = __builtin_amdgcn_mfma_f32_32x32x16_f16(A3[0], Be[0].v8, FZ, 0,0,0);
            Dv = __builtin_amdgcn_mfma_f32_32x32x16_f16(A3[1], Bv[1].v8, Dv, 0,0,0);
            Da = __builtin_amdgcn_mfma_f32_32x32x16_f16(A3[1], Ba[1].v8, Da, 0,0,0);
            Dc = __builtin_amdgcn_mfma_f32_32x32x16_f16(A3[1], Bc[1].v8, Dc, 0,0,0);
            De = __builtin_amdgcn_mfma_f32_32x32x16_f16(A3[1], Be[1].v8, De, 0,0,0);

            #pragma unroll
            for (int r = 0; r < 12; ++r) {
                const float zv = Dv[r], za = Da[r], zc = Dc[r], ze = De[r];
                const float th = tanh_fast(zv);
                const float s  = fmaf(-th, th, 1.0f);
                const float q  = s * zc;
                Dv[r] = th; Da[r] = s * za; Dc[r] = q;
                De[r] = fmaf(s, ze, -((th + th) * q) * zc);
            }

            float u = 0.f, ut = 0.f, ux = 0.f, uxx = 0.f;
            #pragma unroll
            for (int r = 0; r < 12; ++r) {
                u   = fmaf(w4v[r], Dv[r], u);
                ut  = fmaf(w4v[r], Da[r], ut);
                ux  = fmaf(w4v[r], Dc[r], ux);
                uxx = fmaf(w4v[r], De[r], uxx);
            }
            u   = xor32_sum(u) + b4v;
            ut  = xor32_sum(ut);
            ux  = xor32_sum(ux);
            uxx = xor32_sum(uxx);

            float f = fmaf(u, ux, ut);
            f = fmaf(-nu, uxx, f);
            if (h == 0 && valid) lc += f * f;
        } else {
            // ============ initial + boundary: value channel only ============
            auto l1v = [&](int e, int c) -> float {
                const int n = 16 * c + 8 * h + e;
                const float4 w = sL[n];
                return tanh_fast(fmaf(tv, w.x, fmaf(xv, w.y, w.z)));
            };

            H8 Bv[2];
            #pragma unroll
            for (int d2 = 0; d2 < 4; ++d2)
                Bv[0].d[d2] = pk(l1v(2*d2, 0), l1v(2*d2+1, 0));
            #pragma unroll
            for (int d2 = 0; d2 < 2; ++d2)
                Bv[1].d[d2] = pk(l1v(2*d2, 1), l1v(2*d2+1, 1));
            Bv[1].d[2] = ONE0; Bv[1].d[3] = Z2;

            f32x16 Dv;
            Dv = __builtin_amdgcn_mfma_f32_32x32x16_f16(A2[0], Bv[0].v8, FZ, 0,0,0);
            Dv = __builtin_amdgcn_mfma_f32_32x32x16_f16(A2[1], Bv[1].v8, Dv, 0,0,0);
            #pragma unroll
            for (int r = 0; r < 12; ++r) Dv[r] = tanh_fast(Dv[r]);

            #pragma unroll
            for (int d2 = 0; d2 < 2; ++d2) {
                float x0,y0,x1,y1;
                x0=Dv[2*d2]; y0=Dv[4+2*d2]; swap_halves(x0,y0);
                x1=Dv[2*d2+1]; y1=Dv[5+2*d2]; swap_halves(x1,y1);
                Bv[0].d[d2] = pk(x0,x1); Bv[0].d[2+d2] = pk(y0,y1);
            }
            Bv[1].d[0] = pk(Dv[8],Dv[9]); Bv[1].d[1] = pk(Dv[10],Dv[11]);
            Bv[1].d[2] = ONE0; Bv[1].d[3] = Z2;

            Dv = __builtin_amdgcn_mfma_f32_32x32x16_f16(A3[0], Bv[0].v8, FZ, 0,0,0);
            Dv = __builtin_amdgcn_mfma_f32_32x32x16_f16(A3[1], Bv[1].v8, Dv, 0,0,0);
            #pragma unroll
            for (int r = 0; r < 12; ++r) Dv[r] = tanh_fast(Dv[r]);

            float u = 0.f;
            #pragma unroll
            for (int r = 0; r < 12; ++r) u = fmaf(w4v[r], Dv[r], u);
            u = xor32_sum(u) + b4v;
            const float dd = u - uT;
            if (h == 0 && valid) {
                if (t >= ntc + nti) lb += dd * dd; else li += dd * dd;
            }
        }

        t = nxt; tv = ntv; xv = nxv; uT = nuT; valid = nvalid;
    }

    block_reduce_atomic(lc, sums + 0);
    block_reduce_atomic(li, sums + 1);
    block_reduce_atomic(lb, sums + 2);
}

__global__ void k_zero(double* sums) {
    if (threadIdx.x < 3) sums[threadIdx.x] = 0.0;
}

__global__ void k_fin(const double* __restrict__ sums, float* __restrict__ out,
                      int N, int NI, int NB) {
    out[0] = (float)(sums[0] / (double)N + sums[1] / (double)NI + sums[2] / (double)NB);
}

extern "C" void kernel_launch(void* const* d_in, const int* in_sizes, int n_in,
                              void* d_out, int out_size, void* d_ws, size_t ws_size,
                              hipStream_t stream) {
    const float* t_c = (const float*)d_in[0];
    const float* x_c = (const float*)d_in[1];
    const float* t_i = (const float*)d_in[2];
    const float* x_i = (const float*)d_in[3];
    const float* u_i = (const float*)d_in[4];
    const float* t_b = (const float*)d_in[5];
    const float* x_b = (const float*)d_in[6];
    const float* u_b = (const float*)d_in[7];
    const float* W1  = (const float*)d_in[8];
    const float* b1  = (const float*)d_in[9];
    const float* W2  = (const float*)d_in[10];
    const float* b2  = (const float*)d_in[11];
    const float* W3  = (const float*)d_in[12];
    const float* b3  = (const float*)d_in[13];
    const float* W4  = (const float*)d_in[14];
    const float* b4  = (const float*)d_in[15];

    const int N  = in_sizes[0];
    const int NI = in_sizes[2];
    const int NB = in_sizes[5];
    const float nu = 0.0031830988618379067f;  // 0.01/pi

    // 768 blocks = 3 blocks/CU x 256 CUs at 3 waves/SIMD. Unified work queue
    // inside the kernel self-balances coll vs data and leaves <=1-tile tail.
    const int GRID = 768;

    double* sums = (double*)d_ws;

    k_zero<<<1, 64, 0, stream>>>(sums);
    k_fused<<<GRID, 256, 0, stream>>>(t_c, x_c, t_i, x_i, u_i, t_b, x_b, u_b,
                                      W1, b1, W2, b2, W3, b3, W4, b4,
                                      sums, N, NI, NB, nu);
    k_fin<<<1, 1, 0, stream>>>(sums, (float*)d_out, N, NI, NB);
}

// Round 11
// 102.639 us; speedup vs baseline: 1.3362x; 1.0292x over previous
//
#include <hip/hip_runtime.h>

#define HID 20

typedef _Float16 half8  __attribute__((ext_vector_type(8)));
typedef _Float16 half2t __attribute__((ext_vector_type(2)));
typedef float    f32x16 __attribute__((ext_vector_type(16)));

union H8 { half8 v8; half2t d[4]; };   // build fp16 fragment dword-by-dword

// tanh via exp2 + rcp: tanh(v) = 1 - 2/(exp2(v*2*log2e)+1). Saturates at +-inf.
static __device__ __forceinline__ float tanh_fast(float v) {
    const float e = __builtin_amdgcn_exp2f(v * 2.8853900817779268f);
    const float r = __builtin_amdgcn_rcpf(e + 1.0f);
    return fmaf(-2.0f, r, 1.0f);
}

// v_cvt_pkrtz_f16_f32: pack two f32 into one dword of two fp16 (RTZ).
static __device__ __forceinline__ half2t pk(float a, float b) {
    auto r = __builtin_amdgcn_cvt_pkrtz(a, b);
    half2t out;
    __builtin_memcpy(&out, &r, sizeof(out));
    return out;
}

// v_permlane32_swap_b32: new_x[l>=32] = old_y[l-32]; new_y[l<32] = old_x[l+32].
static __device__ __forceinline__ void swap_halves(float& x, float& y) {
    asm("v_permlane32_swap_b32 %0, %1" : "+v"(x), "+v"(y));
}

// sum with lane^32 partner on every lane: permlane-based, no LDS wait.
static __device__ __forceinline__ float xor32_sum(float u) {
    float t = u;
    swap_halves(u, t);
    return u + t;
}

// 64-lane shuffle reduce -> cross-wave LDS -> one f64 atomic per block.
__device__ __forceinline__ void block_reduce_atomic(float local, double* dst) {
    #pragma unroll
    for (int off = 32; off > 0; off >>= 1) local += __shfl_down(local, off);
    __shared__ float parts[4];
    __syncthreads();
    const int lane = threadIdx.x & 63, wid = threadIdx.x >> 6;
    if (lane == 0) parts[wid] = local;
    __syncthreads();
    if (threadIdx.x == 0)
        atomicAdd(dst, (double)(parts[0] + parts[1] + parts[2] + parts[3]));
}

// ---------------------------------------------------------------------------
// Fused kernel, UNIFIED work queue: every wave grid-strides over the combined
// tile space [0, ntc+nti+ntb) and branches per tile (wave-uniform) on class.
// Grid = 1024 = 4 blocks/CU: round-10 compiled to 60 arch VGPR + 64 acc = 124
// <= 128 total, which the HW runs at 4 blocks/CU (16 waves/CU) — round 10's
// 768 grid was the only occupancy cap. Kernel body is byte-identical to the
// round-10 version (no regalloc perturbation).
// Swapped MFMA orientation: D = Wt * Ht, point = column = lane&31 for B and D.
//   A (Wt): M-row = lane&31 (out neuron), k = 16c + 8h + e (in neuron);
//           k==20 carries the bias; rows/cols >= 20 are zero.
//   D:      col = lane&31 (point), row = (r&3) + 8(r>>2) + 4h.
// Rows >= 20 of D are exactly 0 => epilogue only r<12; pack c=1 needs no swap.
// __launch_bounds__(256,3): regalloc hint (NOT an occupancy cap); (256,4)
// forces arch<=64 -> 22 MB scratch spill (measured round 7). Folded finalize
// also triggers spill (measured round 9) -> separate k_fin.
// ---------------------------------------------------------------------------
__global__ __launch_bounds__(256, 3) void k_fused(
    const float* __restrict__ t_c, const float* __restrict__ x_c,
    const float* __restrict__ t_i, const float* __restrict__ x_i, const float* __restrict__ u_i,
    const float* __restrict__ t_b, const float* __restrict__ x_b, const float* __restrict__ u_b,
    const float* __restrict__ W1, const float* __restrict__ b1,
    const float* __restrict__ W2, const float* __restrict__ b2,
    const float* __restrict__ W3, const float* __restrict__ b3,
    const float* __restrict__ W4, const float* __restrict__ b4,
    double* __restrict__ sums,
    int N, int NI, int NB, float nu)
{
    __shared__ float4 sL[32];          // {W1_t, W1_x, b1, 0} per layer-1 slot
    const int tid = threadIdx.x;
    if (tid < 32) {
        const bool r = tid < HID;
        sL[tid] = make_float4(r ? W1[tid] : 0.f, r ? W1[HID + tid] : 0.f,
                              r ? b1[tid] : 0.f, 0.f);
    }
    __syncthreads();

    const int lane = tid & 63;
    const int h    = lane >> 5;
    const int colp = lane & 31;

    // A fragments for W2,W3 (+bias row k=20); W4 in D layout (live rows only)
    half8 A2[2], A3[2];
    #pragma unroll
    for (int c = 0; c < 2; ++c) {
        #pragma unroll
        for (int e = 0; e < 8; ++e) {
            const int i = 16 * c + 8 * h + e;
            float v2 = 0.f, v3 = 0.f;
            if (colp < HID) {
                if (i < HID)       { v2 = W2[i * HID + colp]; v3 = W3[i * HID + colp]; }
                else if (i == HID) { v2 = b2[colp];           v3 = b3[colp]; }
            }
            A2[c][e] = (_Float16)v2;
            A3[c][e] = (_Float16)v3;
        }
    }
    float w4v[12];
    #pragma unroll
    for (int r = 0; r < 12; ++r) {
        const int row = (r & 3) + 8 * (r >> 2) + 4 * h;
        w4v[r] = (row < HID) ? W4[row] : 0.0f;
    }
    const float b4v = b4[0];
    const half2t Z2   = {(_Float16)0.0f, (_Float16)0.0f};
    const half2t ONE0 = {(_Float16)1.0f, (_Float16)0.0f};
    // persistent zero accumulator: C operand of each channel's first MFMA chunk
    f32x16 FZ;
    #pragma unroll
    for (int r = 0; r < 16; ++r) FZ[r] = 0.0f;

    const int ntc  = (N  + 31) >> 5;
    const int nti  = (NI + 31) >> 5;
    const int ntb  = (NB + 31) >> 5;
    const int ntot = ntc + nti + ntb;
    const int gw   = (int)blockIdx.x * 4 + (tid >> 6);
    const int nw   = (int)gridDim.x * 4;

    // fetch inputs for unified tile index t2 (class-aware); wave-uniform t2.
    auto fetch = [&](int t2, float& ftv, float& fxv, float& fuT, bool& fvalid) {
        if (t2 < ntc) {
            const int idx = (t2 << 5) + colp;
            fvalid = idx < N;
            const int ia = fvalid ? idx : 0;
            ftv = t_c[ia]; fxv = x_c[ia]; fuT = 0.f;
        } else {
            const bool isB = t2 >= ntc + nti;
            const float* tp = isB ? t_b : t_i;
            const float* xp = isB ? x_b : x_i;
            const float* up = isB ? u_b : u_i;
            const int    n_ = isB ? NB  : NI;
            const int  base = t2 - ntc - (isB ? nti : 0);
            const int  idx  = (base << 5) + colp;
            fvalid = idx < n_;
            const int ia = fvalid ? idx : 0;
            ftv = tp[ia]; fxv = xp[ia]; fuT = up[ia];
        }
    };

    float lc = 0.f, li = 0.f, lb = 0.f;

    int  t = gw;
    float tv = 0.f, xv = 0.f, uT = 0.f;
    bool valid = false;
    if (t < ntot) fetch(t, tv, xv, uT, valid);

    while (t < ntot) {
        // ---- software prefetch of next tile's inputs (cross-class aware) ----
        const int nxt = t + nw;
        float ntv = 0.f, nxv = 0.f, nuT = 0.f;
        bool nvalid = false;
        if (nxt < ntot) fetch(nxt, ntv, nxv, nuT, nvalid);

        if (t < ntc) {
            // ================= collocation: 4 dual channels =================
            auto l1 = [&](int e, int c, float& vv, float& va, float& vc, float& ve) {
                const int n = 16 * c + 8 * h + e;
                const float4 w = sL[n];
                const float p  = fmaf(tv, w.x, fmaf(xv, w.y, w.z));
                const float th = tanh_fast(p);
                const float s  = fmaf(-th, th, 1.0f);
                const float q  = s * w.y;
                vv = th; va = s * w.x; vc = q; ve = -((th + th) * q) * w.y;
            };

            H8 Bv[2], Ba[2], Bc[2], Be[2];
            #pragma unroll
            for (int d2 = 0; d2 < 4; ++d2) {       // c=0, slot pairs
                float v0,a0,c0,e0, v1,a1,c1,e1;
                l1(2*d2,     0, v0,a0,c0,e0);
                l1(2*d2 + 1, 0, v1,a1,c1,e1);
                Bv[0].d[d2] = pk(v0,v1); Ba[0].d[d2] = pk(a0,a1);
                Bc[0].d[d2] = pk(c0,c1); Be[0].d[d2] = pk(e0,e1);
            }
            #pragma unroll
            for (int d2 = 0; d2 < 2; ++d2) {       // c=1, slots 16..19
                float v0,a0,c0,e0, v1,a1,c1,e1;
                l1(2*d2,     1, v0,a0,c0,e0);
                l1(2*d2 + 1, 1, v1,a1,c1,e1);
                Bv[1].d[d2] = pk(v0,v1); Ba[1].d[d2] = pk(a0,a1);
                Bc[1].d[d2] = pk(c0,c1); Be[1].d[d2] = pk(e0,e1);
            }
            Bv[1].d[2] = ONE0; Ba[1].d[2] = Z2; Bc[1].d[2] = Z2; Be[1].d[2] = Z2;
            Bv[1].d[3] = Z2;   Ba[1].d[3] = Z2; Bc[1].d[3] = Z2; Be[1].d[3] = Z2;

            // ---- layer 2: first chunk takes FZ as C (no per-tile zeroing) ----
            f32x16 Dv, Da, Dc, De;
            Dv = __builtin_amdgcn_mfma_f32_32x32x16_f16(A2[0], Bv[0].v8, FZ, 0,0,0);
            Da = __builtin_amdgcn_mfma_f32_32x32x16_f16(A2[0], Ba[0].v8, FZ, 0,0,0);
            Dc = __builtin_amdgcn_mfma_f32_32x32x16_f16(A2[0], Bc[0].v8, FZ, 0,0,0);
            De = __builtin_amdgcn_mfma_f32_32x32x16_f16(A2[0], Be[0].v8, FZ, 0,0,0);
            Dv = __builtin_amdgcn_mfma_f32_32x32x16_f16(A2[1], Bv[1].v8, Dv, 0,0,0);
            Da = __builtin_amdgcn_mfma_f32_32x32x16_f16(A2[1], Ba[1].v8, Da, 0,0,0);
            Dc = __builtin_amdgcn_mfma_f32_32x32x16_f16(A2[1], Bc[1].v8, Dc, 0,0,0);
            De = __builtin_amdgcn_mfma_f32_32x32x16_f16(A2[1], Be[1].v8, De, 0,0,0);

            #pragma unroll
            for (int r = 0; r < 12; ++r) {          // rows >=24 are dead
                const float zv = Dv[r], za = Da[r], zc = Dc[r], ze = De[r];
                const float th = tanh_fast(zv);
                const float s  = fmaf(-th, th, 1.0f);
                const float q  = s * zc;
                Dv[r] = th; Da[r] = s * za; Dc[r] = q;
                De[r] = fmaf(s, ze, -((th + th) * q) * zc);
            }
            // pack D -> B: c=0 via swaps; c=1 straight (h=1 side is natural 0)
            #pragma unroll
            for (int d2 = 0; d2 < 2; ++d2) {
                float x0,y0,x1,y1;
                x0=Dv[2*d2]; y0=Dv[4+2*d2]; swap_halves(x0,y0);
                x1=Dv[2*d2+1]; y1=Dv[5+2*d2]; swap_halves(x1,y1);
                Bv[0].d[d2] = pk(x0,x1); Bv[0].d[2+d2] = pk(y0,y1);
                x0=Da[2*d2]; y0=Da[4+2*d2]; swap_halves(x0,y0);
                x1=Da[2*d2+1]; y1=Da[5+2*d2]; swap_halves(x1,y1);
                Ba[0].d[d2] = pk(x0,x1); Ba[0].d[2+d2] = pk(y0,y1);
                x0=Dc[2*d2]; y0=Dc[4+2*d2]; swap_halves(x0,y0);
                x1=Dc[2*d2+1]; y1=Dc[5+2*d2]; swap_halves(x1,y1);
                Bc[0].d[d2] = pk(x0,x1); Bc[0].d[2+d2] = pk(y0,y1);
                x0=De[2*d2]; y0=De[4+2*d2]; swap_halves(x0,y0);
                x1=De[2*d2+1]; y1=De[5+2*d2]; swap_halves(x1,y1);
                Be[0].d[d2] = pk(x0,x1); Be[0].d[2+d2] = pk(y0,y1);
            }
            Bv[1].d[0] = pk(Dv[8],Dv[9]); Bv[1].d[1] = pk(Dv[10],Dv[11]);
            Ba[1].d[0] = pk(Da[8],Da[9]); Ba[1].d[1] = pk(Da[10],Da[11]);
            Bc[1].d[0] = pk(Dc[8],Dc[9]); Bc[1].d[1] = pk(Dc[10],Dc[11]);
            Be[1].d[0] = pk(De[8],De[9]); Be[1].d[1] = pk(De[10],De[11]);
            Bv[1].d[2] = ONE0; Ba[1].d[2] = Z2; Bc[1].d[2] = Z2; Be[1].d[2] = Z2;
            Bv[1].d[3] = Z2;   Ba[1].d[3] = Z2; Bc[1].d[3] = Z2; Be[1].d[3] = Z2;

            // ---- layer 3 ----
            Dv = __builtin_amdgcn_mfma_f32_32x32x16_f16(A3[0], Bv[0].v8, FZ, 0,0,0);
            Da = __builtin_amdgcn_mfma_f32_32x32x16_f16(A3[0], Ba[0].v8, FZ, 0,0,0);
            Dc = __builtin_amdgcn_mfma_f32_32x32x16_f16(A3[0], Bc[0].v8, FZ, 0,0,0);
            De = __builtin_amdgcn_mfma_f32_32x32x16_f16(A3[0], Be[0].v8, FZ, 0,0,0);
            Dv = __builtin_amdgcn_mfma_f32_32x32x16_f16(A3[1], Bv[1].v8, Dv, 0,0,0);
            Da = __builtin_amdgcn_mfma_f32_32x32x16_f16(A3[1], Ba[1].v8, Da, 0,0,0);
            Dc = __builtin_amdgcn_mfma_f32_32x32x16_f16(A3[1], Bc[1].v8, Dc, 0,0,0);
            De = __builtin_amdgcn_mfma_f32_32x32x16_f16(A3[1], Be[1].v8, De, 0,0,0);

            #pragma unroll
            for (int r = 0; r < 12; ++r) {
                const float zv = Dv[r], za = Da[r], zc = Dc[r], ze = De[r];
                const float th = tanh_fast(zv);
                const float s  = fmaf(-th, th, 1.0f);
                const float q  = s * zc;
                Dv[r] = th; Da[r] = s * za; Dc[r] = q;
                De[r] = fmaf(s, ze, -((th + th) * q) * zc);
            }

            float u = 0.f, ut = 0.f, ux = 0.f, uxx = 0.f;
            #pragma unroll
            for (int r = 0; r < 12; ++r) {
                u   = fmaf(w4v[r], Dv[r], u);
                ut  = fmaf(w4v[r], Da[r], ut);
                ux  = fmaf(w4v[r], Dc[r], ux);
                uxx = fmaf(w4v[r], De[r], uxx);
            }
            u   = xor32_sum(u) + b4v;
            ut  = xor32_sum(ut);
            ux  = xor32_sum(ux);
            uxx = xor32_sum(uxx);

            float f = fmaf(u, ux, ut);
            f = fmaf(-nu, uxx, f);
            if (h == 0 && valid) lc += f * f;
        } else {
            // ============ initial + boundary: value channel only ============
            auto l1v = [&](int e, int c) -> float {
                const int n = 16 * c + 8 * h + e;
                const float4 w = sL[n];
                return tanh_fast(fmaf(tv, w.x, fmaf(xv, w.y, w.z)));
            };

            H8 Bv[2];
            #pragma unroll
            for (int d2 = 0; d2 < 4; ++d2)
                Bv[0].d[d2] = pk(l1v(2*d2, 0), l1v(2*d2+1, 0));
            #pragma unroll
            for (int d2 = 0; d2 < 2; ++d2)
                Bv[1].d[d2] = pk(l1v(2*d2, 1), l1v(2*d2+1, 1));
            Bv[1].d[2] = ONE0; Bv[1].d[3] = Z2;

            f32x16 Dv;
            Dv = __builtin_amdgcn_mfma_f32_32x32x16_f16(A2[0], Bv[0].v8, FZ, 0,0,0);
            Dv = __builtin_amdgcn_mfma_f32_32x32x16_f16(A2[1], Bv[1].v8, Dv, 0,0,0);
            #pragma unroll
            for (int r = 0; r < 12; ++r) Dv[r] = tanh_fast(Dv[r]);

            #pragma unroll
            for (int d2 = 0; d2 < 2; ++d2) {
                float x0,y0,x1,y1;
                x0=Dv[2*d2]; y0=Dv[4+2*d2]; swap_halves(x0,y0);
                x1=Dv[2*d2+1]; y1=Dv[5+2*d2]; swap_halves(x1,y1);
                Bv[0].d[d2] = pk(x0,x1); Bv[0].d[2+d2] = pk(y0,y1);
            }
            Bv[1].d[0] = pk(Dv[8],Dv[9]); Bv[1].d[1] = pk(Dv[10],Dv[11]);
            Bv[1].d[2] = ONE0; Bv[1].d[3] = Z2;

            Dv = __builtin_amdgcn_mfma_f32_32x32x16_f16(A3[0], Bv[0].v8, FZ, 0,0,0);
            Dv = __builtin_amdgcn_mfma_f32_32x32x16_f16(A3[1], Bv[1].v8, Dv, 0,0,0);
            #pragma unroll
            for (int r = 0; r < 12; ++r) Dv[r] = tanh_fast(Dv[r]);

            float u = 0.f;
            #pragma unroll
            for (int r = 0; r < 12; ++r) u = fmaf(w4v[r], Dv[r], u);
            u = xor32_sum(u) + b4v;
            const float dd = u - uT;
            if (h == 0 && valid) {
                if (t >= ntc + nti) lb += dd * dd; else li += dd * dd;
            }
        }

        t = nxt; tv = ntv; xv = nxv; uT = nuT; valid = nvalid;
    }

    block_reduce_atomic(lc, sums + 0);
    block_reduce_atomic(li, sums + 1);
    block_reduce_atomic(lb, sums + 2);
}

__global__ void k_zero(double* sums) {
    if (threadIdx.x < 3) sums[threadIdx.x] = 0.0;
}

__global__ void k_fin(const double* __restrict__ sums, float* __restrict__ out,
                      int N, int NI, int NB) {
    out[0] = (float)(sums[0] / (double)N + sums[1] / (double)NI + sums[2] / (double)NB);
}

extern "C" void kernel_launch(void* const* d_in, const int* in_sizes, int n_in,
                              void* d_out, int out_size, void* d_ws, size_t ws_size,
                              hipStream_t stream) {
    const float* t_c = (const float*)d_in[0];
    const float* x_c = (const float*)d_in[1];
    const float* t_i = (const float*)d_in[2];
    const float* x_i = (const float*)d_in[3];
    const float* u_i = (const float*)d_in[4];
    const float* t_b = (const float*)d_in[5];
    const float* x_b = (const float*)d_in[6];
    const float* u_b = (const float*)d_in[7];
    const float* W1  = (const float*)d_in[8];
    const float* b1  = (const float*)d_in[9];
    const float* W2  = (const float*)d_in[10];
    const float* b2  = (const float*)d_in[11];
    const float* W3  = (const float*)d_in[12];
    const float* b3  = (const float*)d_in[13];
    const float* W4  = (const float*)d_in[14];
    const float* b4  = (const float*)d_in[15];

    const int N  = in_sizes[0];
    const int NI = in_sizes[2];
    const int NB = in_sizes[5];
    const float nu = 0.0031830988618379067f;  // 0.01/pi

    // 1024 blocks = 4 blocks/CU x 256 CUs: fits because round-10 compiled to
    // 60 arch + 64 acc = 124 <= 128 regs. Unified work queue self-balances.
    const int GRID = 1024;

    double* sums = (double*)d_ws;

    k_zero<<<1, 64, 0, stream>>>(sums);
    k_fused<<<GRID, 256, 0, stream>>>(t_c, x_c, t_i, x_i, u_i, t_b, x_b, u_b,
                                      W1, b1, W2, b2, W3, b3, W4, b4,
                                      sums, N, NI, NB, nu);
    k_fin<<<1, 1, 0, stream>>>(sums, (float*)d_out, N, NI, NB);
}

// Round 13
// 102.567 us; speedup vs baseline: 1.3372x; 1.0007x over previous
//
#include <hip/hip_runtime.h>

#define HID 20

typedef _Float16 half8  __attribute__((ext_vector_type(8)));
typedef _Float16 half2t __attribute__((ext_vector_type(2)));
typedef float    f32x16 __attribute__((ext_vector_type(16)));

union H8 { half8 v8; half2t d[4]; };   // build fp16 fragment dword-by-dword

// tanh via exp2 + rcp: tanh(v) = 1 - 2/(exp2(v*2*log2e)+1). Saturates at +-inf.
static __device__ __forceinline__ float tanh_fast(float v) {
    const float e = __builtin_amdgcn_exp2f(v * 2.8853900817779268f);
    const float r = __builtin_amdgcn_rcpf(e + 1.0f);
    return fmaf(-2.0f, r, 1.0f);
}

// v_cvt_pkrtz_f16_f32: pack two f32 into one dword of two fp16 (RTZ).
static __device__ __forceinline__ half2t pk(float a, float b) {
    auto r = __builtin_amdgcn_cvt_pkrtz(a, b);
    half2t out;
    __builtin_memcpy(&out, &r, sizeof(out));
    return out;
}

// v_permlane32_swap_b32: new_x[l>=32] = old_y[l-32]; new_y[l<32] = old_x[l+32].
static __device__ __forceinline__ void swap_halves(float& x, float& y) {
    asm("v_permlane32_swap_b32 %0, %1" : "+v"(x), "+v"(y));
}

// sum with lane^32 partner on every lane: permlane-based, no LDS wait.
static __device__ __forceinline__ float xor32_sum(float u) {
    float t = u;
    swap_halves(u, t);
    return u + t;
}

// 64-lane shuffle reduce -> cross-wave LDS -> one f64 atomic per block.
__device__ __forceinline__ void block_reduce_atomic(float local, double* dst) {
    #pragma unroll
    for (int off = 32; off > 0; off >>= 1) local += __shfl_down(local, off);
    __shared__ float parts[4];
    __syncthreads();
    const int lane = threadIdx.x & 63, wid = threadIdx.x >> 6;
    if (lane == 0) parts[wid] = local;
    __syncthreads();
    if (threadIdx.x == 0)
        atomicAdd(dst, (double)(parts[0] + parts[1] + parts[2] + parts[3]));
}

// ---------------------------------------------------------------------------
// Fused kernel, UNIFIED work queue over [0, ntc+nti+ntb); wave-uniform class
// branch per tile. Grid = 1024 = 4 blocks/CU (60 arch + 64 acc = 124 <= 128).
// PROVEN round-11 configuration (102.6 us, absmax 0) restored verbatim:
//  - swap-first D->B repack (pk-first variant NaN'd in round 12);
//  - k_zero kernel for accumulator init (hipMemsetAsync variant bundled with
//    the NaN round; not re-risked);
//  - __launch_bounds__(256,3) regalloc hint; (256,4) forces arch<=64 ->
//    22 MB scratch spill (measured round 7); folded finalize spills (round 9).
// Swapped MFMA orientation: D = Wt * Ht, point = column = lane&31 for B and D.
//   A (Wt): M-row = lane&31 (out neuron), k = 16c + 8h + e (in neuron);
//           k==20 carries the bias; rows/cols >= 20 are zero.
//   D:      col = lane&31 (point), row = (r&3) + 8(r>>2) + 4h.
// Rows >= 20 of D are exactly 0 => epilogue only r<12; pack c=1 needs no swap.
// ---------------------------------------------------------------------------
__global__ __launch_bounds__(256, 3) void k_fused(
    const float* __restrict__ t_c, const float* __restrict__ x_c,
    const float* __restrict__ t_i, const float* __restrict__ x_i, const float* __restrict__ u_i,
    const float* __restrict__ t_b, const float* __restrict__ x_b, const float* __restrict__ u_b,
    const float* __restrict__ W1, const float* __restrict__ b1,
    const float* __restrict__ W2, const float* __restrict__ b2,
    const float* __restrict__ W3, const float* __restrict__ b3,
    const float* __restrict__ W4, const float* __restrict__ b4,
    double* __restrict__ sums,
    int N, int NI, int NB, float nu)
{
    __shared__ float4 sL[32];          // {W1_t, W1_x, b1, 0} per layer-1 slot
    const int tid = threadIdx.x;
    if (tid < 32) {
        const bool r = tid < HID;
        sL[tid] = make_float4(r ? W1[tid] : 0.f, r ? W1[HID + tid] : 0.f,
                              r ? b1[tid] : 0.f, 0.f);
    }
    __syncthreads();

    const int lane = tid & 63;
    const int h    = lane >> 5;
    const int colp = lane & 31;

    // A fragments for W2,W3 (+bias row k=20); W4 in D layout (live rows only)
    half8 A2[2], A3[2];
    #pragma unroll
    for (int c = 0; c < 2; ++c) {
        #pragma unroll
        for (int e = 0; e < 8; ++e) {
            const int i = 16 * c + 8 * h + e;
            float v2 = 0.f, v3 = 0.f;
            if (colp < HID) {
                if (i < HID)       { v2 = W2[i * HID + colp]; v3 = W3[i * HID + colp]; }
                else if (i == HID) { v2 = b2[colp];           v3 = b3[colp]; }
            }
            A2[c][e] = (_Float16)v2;
            A3[c][e] = (_Float16)v3;
        }
    }
    float w4v[12];
    #pragma unroll
    for (int r = 0; r < 12; ++r) {
        const int row = (r & 3) + 8 * (r >> 2) + 4 * h;
        w4v[r] = (row < HID) ? W4[row] : 0.0f;
    }
    const float b4v = b4[0];
    const half2t Z2   = {(_Float16)0.0f, (_Float16)0.0f};
    const half2t ONE0 = {(_Float16)1.0f, (_Float16)0.0f};
    // persistent zero accumulator: C operand of each channel's first MFMA chunk
    f32x16 FZ;
    #pragma unroll
    for (int r = 0; r < 16; ++r) FZ[r] = 0.0f;

    const int ntc  = (N  + 31) >> 5;
    const int nti  = (NI + 31) >> 5;
    const int ntb  = (NB + 31) >> 5;
    const int ntot = ntc + nti + ntb;
    const int gw   = (int)blockIdx.x * 4 + (tid >> 6);
    const int nw   = (int)gridDim.x * 4;

    // fetch inputs for unified tile index t2 (class-aware); wave-uniform t2.
    auto fetch = [&](int t2, float& ftv, float& fxv, float& fuT, bool& fvalid) {
        if (t2 < ntc) {
            const int idx = (t2 << 5) + colp;
            fvalid = idx < N;
            const int ia = fvalid ? idx : 0;
            ftv = t_c[ia]; fxv = x_c[ia]; fuT = 0.f;
        } else {
            const bool isB = t2 >= ntc + nti;
            const float* tp = isB ? t_b : t_i;
            const float* xp = isB ? x_b : x_i;
            const float* up = isB ? u_b : u_i;
            const int    n_ = isB ? NB  : NI;
            const int  base = t2 - ntc - (isB ? nti : 0);
            const int  idx  = (base << 5) + colp;
            fvalid = idx < n_;
            const int ia = fvalid ? idx : 0;
            ftv = tp[ia]; fxv = xp[ia]; fuT = up[ia];
        }
    };

    float lc = 0.f, li = 0.f, lb = 0.f;

    int  t = gw;
    float tv = 0.f, xv = 0.f, uT = 0.f;
    bool valid = false;
    if (t < ntot) fetch(t, tv, xv, uT, valid);

    while (t < ntot) {
        // ---- software prefetch of next tile's inputs (cross-class aware) ----
        const int nxt = t + nw;
        float ntv = 0.f, nxv = 0.f, nuT = 0.f;
        bool nvalid = false;
        if (nxt < ntot) fetch(nxt, ntv, nxv, nuT, nvalid);

        if (t < ntc) {
            // ================= collocation: 4 dual channels =================
            auto l1 = [&](int e, int c, float& vv, float& va, float& vc, float& ve) {
                const int n = 16 * c + 8 * h + e;
                const float4 w = sL[n];
                const float p  = fmaf(tv, w.x, fmaf(xv, w.y, w.z));
                const float th = tanh_fast(p);
                const float s  = fmaf(-th, th, 1.0f);
                const float q  = s * w.y;
                vv = th; va = s * w.x; vc = q; ve = -((th + th) * q) * w.y;
            };

            H8 Bv[2], Ba[2], Bc[2], Be[2];
            #pragma unroll
            for (int d2 = 0; d2 < 4; ++d2) {       // c=0, slot pairs
                float v0,a0,c0,e0, v1,a1,c1,e1;
                l1(2*d2,     0, v0,a0,c0,e0);
                l1(2*d2 + 1, 0, v1,a1,c1,e1);
                Bv[0].d[d2] = pk(v0,v1); Ba[0].d[d2] = pk(a0,a1);
                Bc[0].d[d2] = pk(c0,c1); Be[0].d[d2] = pk(e0,e1);
            }
            #pragma unroll
            for (int d2 = 0; d2 < 2; ++d2) {       // c=1, slots 16..19
                float v0,a0,c0,e0, v1,a1,c1,e1;
                l1(2*d2,     1, v0,a0,c0,e0);
                l1(2*d2 + 1, 1, v1,a1,c1,e1);
                Bv[1].d[d2] = pk(v0,v1); Ba[1].d[d2] = pk(a0,a1);
                Bc[1].d[d2] = pk(c0,c1); Be[1].d[d2] = pk(e0,e1);
            }
            Bv[1].d[2] = ONE0; Ba[1].d[2] = Z2; Bc[1].d[2] = Z2; Be[1].d[2] = Z2;
            Bv[1].d[3] = Z2;   Ba[1].d[3] = Z2; Bc[1].d[3] = Z2; Be[1].d[3] = Z2;

            // ---- layer 2: first chunk takes FZ as C (no per-tile zeroing) ----
            f32x16 Dv, Da, Dc, De;
            Dv = __builtin_amdgcn_mfma_f32_32x32x16_f16(A2[0], Bv[0].v8, FZ, 0,0,0);
            Da = __builtin_amdgcn_mfma_f32_32x32x16_f16(A2[0], Ba[0].v8, FZ, 0,0,0);
            Dc = __builtin_amdgcn_mfma_f32_32x32x16_f16(A2[0], Bc[0].v8, FZ, 0,0,0);
            De = __builtin_amdgcn_mfma_f32_32x32x16_f16(A2[0], Be[0].v8, FZ, 0,0,0);
            Dv = __builtin_amdgcn_mfma_f32_32x32x16_f16(A2[1], Bv[1].v8, Dv, 0,0,0);
            Da = __builtin_amdgcn_mfma_f32_32x32x16_f16(A2[1], Ba[1].v8, Da, 0,0,0);
            Dc = __builtin_amdgcn_mfma_f32_32x32x16_f16(A2[1], Bc[1].v8, Dc, 0,0,0);
            De = __builtin_amdgcn_mfma_f32_32x32x16_f16(A2[1], Be[1].v8, De, 0,0,0);

            #pragma unroll
            for (int r = 0; r < 12; ++r) {          // rows >=24 are dead
                const float zv = Dv[r], za = Da[r], zc = Dc[r], ze = De[r];
                const float th = tanh_fast(zv);
                const float s  = fmaf(-th, th, 1.0f);
                const float q  = s * zc;
                Dv[r] = th; Da[r] = s * za; Dc[r] = q;
                De[r] = fmaf(s, ze, -((th + th) * q) * zc);
            }
            // pack D -> B: c=0 via swaps; c=1 straight (h=1 side is natural 0)
            #pragma unroll
            for (int d2 = 0; d2 < 2; ++d2) {
                float x0,y0,x1,y1;
                x0=Dv[2*d2]; y0=Dv[4+2*d2]; swap_halves(x0,y0);
                x1=Dv[2*d2+1]; y1=Dv[5+2*d2]; swap_halves(x1,y1);
                Bv[0].d[d2] = pk(x0,x1); Bv[0].d[2+d2] = pk(y0,y1);
                x0=Da[2*d2]; y0=Da[4+2*d2]; swap_halves(x0,y0);
                x1=Da[2*d2+1]; y1=Da[5+2*d2]; swap_halves(x1,y1);
                Ba[0].d[d2] = pk(x0,x1); Ba[0].d[2+d2] = pk(y0,y1);
                x0=Dc[2*d2]; y0=Dc[4+2*d2]; swap_halves(x0,y0);
                x1=Dc[2*d2+1]; y1=Dc[5+2*d2]; swap_halves(x1,y1);
                Bc[0].d[d2] = pk(x0,x1); Bc[0].d[2+d2] = pk(y0,y1);
                x0=De[2*d2]; y0=De[4+2*d2]; swap_halves(x0,y0);
                x1=De[2*d2+1]; y1=De[5+2*d2]; swap_halves(x1,y1);
                Be[0].d[d2] = pk(x0,x1); Be[0].d[2+d2] = pk(y0,y1);
            }
            Bv[1].d[0] = pk(Dv[8],Dv[9]); Bv[1].d[1] = pk(Dv[10],Dv[11]);
            Ba[1].d[0] = pk(Da[8],Da[9]); Ba[1].d[1] = pk(Da[10],Da[11]);
            Bc[1].d[0] = pk(Dc[8],Dc[9]); Bc[1].d[1] = pk(Dc[10],Dc[11]);
            Be[1].d[0] = pk(De[8],De[9]); Be[1].d[1] = pk(De[10],De[11]);
            Bv[1].d[2] = ONE0; Ba[1].d[2] = Z2; Bc[1].d[2] = Z2; Be[1].d[2] = Z2;
            Bv[1].d[3] = Z2;   Ba[1].d[3] = Z2; Bc[1].d[3] = Z2; Be[1].d[3] = Z2;

            // ---- layer 3 ----
            Dv = __builtin_amdgcn_mfma_f32_32x32x16_f16(A3[0], Bv[0].v8, FZ, 0,0,0);
            Da = __builtin_amdgcn_mfma_f32_32x32x16_f16(A3[0], Ba[0].v8, FZ, 0,0,0);
            Dc = __builtin_amdgcn_mfma_f32_32x32x16_f16(A3[0], Bc[0].v8, FZ, 0,0,0);
            De = __builtin_amdgcn_mfma_f32_32x32x16_f16(A3[0], Be[0].v8, FZ, 0,0,0);
            Dv = __builtin_amdgcn_mfma_f32_32x32x16_f16(A3[1], Bv[1].v8, Dv, 0,0,0);
            Da = __builtin_amdgcn_mfma_f32_32x32x16_f16(A3[1], Ba[1].v8, Da, 0,0,0);
            Dc = __builtin_amdgcn_mfma_f32_32x32x16_f16(A3[1], Bc[1].v8, Dc, 0,0,0);
            De = __builtin_amdgcn_mfma_f32_32x32x16_f16(A3[1], Be[1].v8, De, 0,0,0);

            #pragma unroll
            for (int r = 0; r < 12; ++r) {
                const float zv = Dv[r], za = Da[r], zc = Dc[r], ze = De[r];
                const float th = tanh_fast(zv);
                const float s  = fmaf(-th, th, 1.0f);
                const float q  = s * zc;
                Dv[r] = th; Da[r] = s * za; Dc[r] = q;
                De[r] = fmaf(s, ze, -((th + th) * q) * zc);
            }

            float u = 0.f, ut = 0.f, ux = 0.f, uxx = 0.f;
            #pragma unroll
            for (int r = 0; r < 12; ++r) {
                u   = fmaf(w4v[r], Dv[r], u);
                ut  = fmaf(w4v[r], Da[r], ut);
                ux  = fmaf(w4v[r], Dc[r], ux);
                uxx = fmaf(w4v[r], De[r], uxx);
            }
            u   = xor32_sum(u) + b4v;
            ut  = xor32_sum(ut);
            ux  = xor32_sum(ux);
            uxx = xor32_sum(uxx);

            float f = fmaf(u, ux, ut);
            f = fmaf(-nu, uxx, f);
            if (h == 0 && valid) lc += f * f;
        } else {
            // ============ initial + boundary: value channel only ============
            auto l1v = [&](int e, int c) -> float {
                const int n = 16 * c + 8 * h + e;
                const float4 w = sL[n];
                return tanh_fast(fmaf(tv, w.x, fmaf(xv, w.y, w.z)));
            };

            H8 Bv[2];
            #pragma unroll
            for (int d2 = 0; d2 < 4; ++d2)
                Bv[0].d[d2] = pk(l1v(2*d2, 0), l1v(2*d2+1, 0));
            #pragma unroll
            for (int d2 = 0; d2 < 2; ++d2)
                Bv[1].d[d2] = pk(l1v(2*d2, 1), l1v(2*d2+1, 1));
            Bv[1].d[2] = ONE0; Bv[1].d[3] = Z2;

            f32x16 Dv;
            Dv = __builtin_amdgcn_mfma_f32_32x32x16_f16(A2[0], Bv[0].v8, FZ, 0,0,0);
            Dv = __builtin_amdgcn_mfma_f32_32x32x16_f16(A2[1], Bv[1].v8, Dv, 0,0,0);
            #pragma unroll
            for (int r = 0; r < 12; ++r) Dv[r] = tanh_fast(Dv[r]);

            #pragma unroll
            for (int d2 = 0; d2 < 2; ++d2) {
                float x0,y0,x1,y1;
                x0=Dv[2*d2]; y0=Dv[4+2*d2]; swap_halves(x0,y0);
                x1=Dv[2*d2+1]; y1=Dv[5+2*d2]; swap_halves(x1,y1);
                Bv[0].d[d2] = pk(x0,x1); Bv[0].d[2+d2] = pk(y0,y1);
            }
            Bv[1].d[0] = pk(Dv[8],Dv[9]); Bv[1].d[1] = pk(Dv[10],Dv[11]);
            Bv[1].d[2] = ONE0; Bv[1].d[3] = Z2;

            Dv = __builtin_amdgcn_mfma_f32_32x32x16_f16(A3[0], Bv[0].v8, FZ, 0,0,0);
            Dv = __builtin_amdgcn_mfma_f32_32x32x16_f16(A3[1], Bv[1].v8, Dv, 0,0,0);
            #pragma unroll
            for (int r = 0; r < 12; ++r) Dv[r] = tanh_fast(Dv[r]);

            float u = 0.f;
            #pragma unroll
            for (int r = 0; r < 12; ++r) u = fmaf(w4v[r], Dv[r], u);
            u = xor32_sum(u) + b4v;
            const float dd = u - uT;
            if (h == 0 && valid) {
                if (t >= ntc + nti) lb += dd * dd; else li += dd * dd;
            }
        }

        t = nxt; tv = ntv; xv = nxv; uT = nuT; valid = nvalid;
    }

    block_reduce_atomic(lc, sums + 0);
    block_reduce_atomic(li, sums + 1);
    block_reduce_atomic(lb, sums + 2);
}

__global__ void k_zero(double* sums) {
    if (threadIdx.x < 3) sums[threadIdx.x] = 0.0;
}

__global__ void k_fin(const double* __restrict__ sums, float* __restrict__ out,
                      int N, int NI, int NB) {
    out[0] = (float)(sums[0] / (double)N + sums[1] / (double)NI + sums[2] / (double)NB);
}

extern "C" void kernel_launch(void* const* d_in, const int* in_sizes, int n_in,
                              void* d_out, int out_size, void* d_ws, size_t ws_size,
                              hipStream_t stream) {
    const float* t_c = (const float*)d_in[0];
    const float* x_c = (const float*)d_in[1];
    const float* t_i = (const float*)d_in[2];
    const float* x_i = (const float*)d_in[3];
    const float* u_i = (const float*)d_in[4];
    const float* t_b = (const float*)d_in[5];
    const float* x_b = (const float*)d_in[6];
    const float* u_b = (const float*)d_in[7];
    const float* W1  = (const float*)d_in[8];
    const float* b1  = (const float*)d_in[9];
    const float* W2  = (const float*)d_in[10];
    const float* b2  = (const float*)d_in[11];
    const float* W3  = (const float*)d_in[12];
    const float* b3  = (const float*)d_in[13];
    const float* W4  = (const float*)d_in[14];
    const float* b4  = (const float*)d_in[15];

    const int N  = in_sizes[0];
    const int NI = in_sizes[2];
    const int NB = in_sizes[5];
    const float nu = 0.0031830988618379067f;  // 0.01/pi

    // 1024 blocks = 4 blocks/CU x 256 CUs (60 arch + 64 acc = 124 <= 128).
    const int GRID = 1024;

    double* sums = (double*)d_ws;

    k_zero<<<1, 64, 0, stream>>>(sums);
    k_fused<<<GRID, 256, 0, stream>>>(t_c, x_c, t_i, x_i, u_i, t_b, x_b, u_b,
                                      W1, b1, W2, b2, W3, b3, W4, b4,
                                      sums, N, NI, NB, nu);
    k_fin<<<1, 1, 0, stream>>>(sums, (float*)d_out, N, NI, NB);
}